// Round 6
// baseline (26665.103 us; speedup 1.0000x reference)
//
#include <hip/hip_runtime.h>
#include <math.h>

typedef float vf4 __attribute__((ext_vector_type(4)));

// Problem dims (fixed by reference)
constexpr int T  = 512;
constexpr int BB = 64;    // batch
constexpr int II = 256;   // input
constexpr int HH = 512;   // hidden

// d_out layout (floats): out[B,T,H] | s[2,B,H] | h[2,B,H] | c[2,B,H]
constexpr int SOFF = BB * T * HH;          // 16777216
constexpr int HOFF = SOFF + 2 * BB * HH;
constexpr int COFF = HOFF + 2 * BB * HH;

// Workspace layout (float offsets). ~15.3 MB.
constexpr int WS_WC0 = 0;          // [512 j][768 k] vf4  (Wx0;Wh0 stacked)
constexpr int WS_WC1 = 1572864;    // [512 j][1024 k] vf4 (Wx1;Wh1 stacked)
constexpr int WS_BH0 = 3670016;    // [512] vf4
constexpr int WS_BH1 = 3672064;
constexpr int WS_HX0 = 3674112;    // h0 exchange: [2 slot][8 g][8 b][512 j] f
constexpr int WS_HX1 = 3739648;    // h1 exchange: same
constexpr int WS_SX  = 3805184;    // spike words: [4 slot][8 g][64 w] u64
constexpr int WS_FLG = 3809280;    // stamps: [8 g][64] u32

// ---------------- MALL-coherent primitives: plain sc0 sc1 ops, no atomics ----
__device__ __forceinline__ void bypass_st(float* p, float v) {
  asm volatile("global_store_dword %0, %1, off sc0 sc1" :: "v"(p), "v"(v) : "memory");
}
__device__ __forceinline__ void bypass_st_u32(unsigned* p, unsigned v) {
  asm volatile("global_store_dword %0, %1, off sc0 sc1" :: "v"(p), "v"(v) : "memory");
}
__device__ __forceinline__ void bypass_st64(unsigned long long* p, unsigned long long v) {
  asm volatile("global_store_dwordx2 %0, %1, off sc0 sc1" :: "v"(p), "v"(v) : "memory");
}
__device__ __forceinline__ unsigned bypass_ldu(const unsigned* p) {
  unsigned r;
  asm volatile("global_load_dword %0, %1, off sc0 sc1\n\ts_waitcnt vmcnt(0)"
               : "=v"(r) : "v"(p) : "memory");
  return r;
}
__device__ __forceinline__ unsigned long long bypass_ld64(const unsigned long long* p) {
  unsigned long long r;
  asm volatile("global_load_dwordx2 %0, %1, off sc0 sc1\n\ts_waitcnt vmcnt(0)"
               : "=v"(r) : "v"(p) : "memory");
  return r;
}
// two 16B loads, ONE wait (batched latency)
__device__ __forceinline__ void bypass_ld2x4(const vf4* p0, const vf4* p1, vf4& r0, vf4& r1) {
  asm volatile(
      "global_load_dwordx4 %0, %2, off sc0 sc1\n\t"
      "global_load_dwordx4 %1, %3, off sc0 sc1\n\t"
      "s_waitcnt vmcnt(0)"
      : "=&v"(r0), "=&v"(r1) : "v"(p0), "v"(p1) : "memory");
}

__device__ __forceinline__ float sigf(float x) { return 1.0f / (1.0f + __expf(-x)); }
__device__ __forceinline__ float tanh_fast(float x) {
  return 1.0f - 2.0f / (1.0f + __expf(2.0f * x));
}

// ---------------- setup kernels ----------------
// Wp[j][k] f4 = gates (i,f,g,o) of column j, act-row k; rows k<Ka from A, else B.
__global__ void pack_wc(const float* __restrict__ A, const float* __restrict__ B,
                        int Ka, int K, float* __restrict__ Wp) {
  const int j = blockIdx.x;
  for (int k = threadIdx.x; k < K; k += 256) {
    const float* src = (k < Ka) ? (A + (size_t)k * 2048) : (B + (size_t)(k - Ka) * 2048);
    vf4 v = {src[j], src[512 + j], src[1024 + j], src[1536 + j]};
    ((vf4*)Wp)[(size_t)j * K + k] = v;
  }
}

__global__ void pack_bias(const float* __restrict__ bh0, const float* __restrict__ bh1,
                          float* __restrict__ bh0p, float* __restrict__ bh1p) {
  const int i = blockIdx.x * blockDim.x + threadIdx.x;  // 4096
  if (i < 2048) {
    bh0p[i] = bh0[(i & 3) * 512 + (i >> 2)];
  } else {
    int q = i - 2048;
    bh1p[q] = bh1[(q & 3) * 512 + (q >> 2)];
  }
}

// ---------------- main persistent kernel ----------------
// Round 6: 256 blocks x 1024 threads (16 waves/CU, 2x round 5's TLP).
//   xcd = wg & 7; a = wg >> 3; g = a & 7 (batch group, 8 batches);
//   s = (a >> 3) * 8 + xcd  in [0,32) (j-slice of 16 cols) -> per-XCD weight
//   working set 1.84 MB, L2-resident (verified round 5: FETCH collapsed 44x).
// Dot lane mapping (distinct-address): tid = b*128 + jo*8 + kl
//   (b = tid>>7 in [0,8), jo = (tid>>3)&15, kl = tid&7). A wave spans 8 jo x 8 kl
//   -> 64 DISTINCT weight addresses per global_load_dwordx4 (1 KB coalesced,
//   no redundant lanes); LDS cat reads are 8-way same-address broadcast (free).
// Staging: one batched bypass window per step (h0(t)+h1(t-1) in one 2-load
//   1-wait pair per thread), fused with cat1 bit-expansion and x(t+1) load.
// Sync: per-group 32-block stamp-store + poll barrier (round-5 protocol).
__global__ __launch_bounds__(1024) void aslstm_main(
    const vf4* __restrict__ Wc0p, const vf4* __restrict__ Wc1p,
    const vf4* __restrict__ bh0p, const vf4* __restrict__ bh1p,
    const float* __restrict__ x,
    float* __restrict__ hx0, float* __restrict__ hx1,
    unsigned long long* __restrict__ sx,
    unsigned* __restrict__ flags,
    float* __restrict__ out) {
  const int wg  = blockIdx.x;
  const int xcd = wg & 7;
  const int a   = wg >> 3;
  const int g   = a & 7;
  const int s   = (a >> 3) * 8 + xcd;
  const int tid = threadIdx.x;
  // dot mapping
  const int b   = tid >> 7;
  const int jo  = (tid >> 3) & 15;
  const int kl  = tid & 7;
  const int j   = s * 16 + jo;
  // finalize mapping (tid<128)
  const int fjo = tid & 15;
  const int fb  = tid >> 4;
  const int fj  = s * 16 + fjo;

  __shared__ float cat0[8][776];      // [b][ x(256) | h0(512) | pad ]
  __shared__ float cat1[8][1032];     // [b][ s0(512) | h1(512) | pad ]
  __shared__ vf4  part[16][8][9];     // [jo][b][kl] (pad 9)
  __shared__ unsigned long long swords[64];

  float c0 = 0.0f, c1 = 0.0f, sp = 0.0f;

  // staging indices (all threads): one vf4 of h per thread per buffer
  const int sb = tid >> 7;            // batch 0..7
  const int sj = (tid & 127) * 4;     // j 0..508 step 4

  // ---- initial cat0: x[t=0] (tid<512) + h0[-1]=0 (hx0 slot 1 is memset) ----
  {
    if (tid < 512) {
      int bx = tid >> 6, kx = (tid & 63) * 4;
      *(vf4*)&cat0[bx][kx] = *(const vf4*)&x[(size_t)(g * 8 + bx) * (T * II) + kx];
    }
    const vf4* hp = (const vf4*)(hx0 + 32768 + g * 4096 + sb * 512 + sj);
    vf4 r0, r1;  bypass_ld2x4(hp, hp, r0, r1);
    *(vf4*)&cat0[sb][256 + sj] = r0;
  }
  __syncthreads();

  for (int t = 0; t < T; ++t) {
    // ---------- dot0: [x_t ; h0[t-1]] @ Wc0 (K=768) ----------
    {
      const vf4* wr = Wc0p + (size_t)j * 768;
      vf4 acc = {0, 0, 0, 0};
#pragma unroll 4
      for (int q = 0; q < 24; ++q) {
        int k = q * 32 + kl * 4;
        vf4 w0 = wr[k], w1 = wr[k + 1], w2 = wr[k + 2], w3 = wr[k + 3];
        vf4 av = *(const vf4*)&cat0[b][k];
        acc += av.x * w0; acc += av.y * w1; acc += av.z * w2; acc += av.w * w3;
      }
      part[jo][b][kl] = acc;
    }
    __syncthreads();  // S1

    // ---------- finalize layer 0: gates, spike, publish ----------
    if (tid < 128) {
      vf4 p = part[fjo][fb][0];
#pragma unroll
      for (int kk = 1; kk < 8; ++kk) p += part[fjo][fb][kk];
      p += bh0p[fj];
      float cn  = sigf(p.y) * c0 + sigf(p.x) * tanh_fast(p.z);
      float mem = sigf(p.w) * tanh_fast(cn);   // s*0.2*(1-s) == 0 for s in {0,1}
      float sn  = (mem > 0.5f) ? 1.0f : 0.0f;
      c0 = cn; sp = sn;
      bypass_st(&hx0[(t & 1) * 32768 + g * 4096 + fb * 512 + fj], mem);
      unsigned long long ball = __ballot(sn != 0.0f);   // 64-lane wave ballot
      if ((tid & 63) == 0)
        bypass_st64(&sx[(size_t)(t & 3) * 512 + g * 64 + s * 2 + (tid >> 6)], ball);
      if (t == T - 1) {
        out[SOFF + (g * 8 + fb) * 512 + fj] = sn;
        out[HOFF + (g * 8 + fb) * 512 + fj] = mem;
        out[COFF + (g * 8 + fb) * 512 + fj] = cn;
      }
    }
    __syncthreads();  // S2 — per-wave vmcnt drain guarantees publishes are out

    // ---------- group barrier: stamp store + poll (no atomics) ----------
    if (tid == 0) bypass_st_u32(&flags[g * 64 + s], (unsigned)(t + 1));
    if (tid < 64) {
      const unsigned tgt = (unsigned)(t + 1);
      for (;;) {
        unsigned v = bypass_ldu(&flags[g * 64 + (tid & 31)]);
        if (__all((int)(v >= tgt))) break;
        __builtin_amdgcn_s_sleep(1);
      }
      swords[tid] = bypass_ld64(&sx[(size_t)(t & 3) * 512 + g * 64 + tid]);
    }
    __syncthreads();  // S3

    // ---------- batched staging: cat1(s0,h1) + cat0(x,h0) for t+1 ----------
    {
      // h1(t-1) and h0(t): one 2-load/1-wait pair per thread
      const vf4* hp1 = (const vf4*)(hx1 + ((t + 1) & 1) * 32768 + g * 4096 + sb * 512 + sj);
      const vf4* hp0 = (const vf4*)(hx0 + (t & 1) * 32768 + g * 4096 + sb * 512 + sj);
      vf4 r1, r0;  bypass_ld2x4(hp1, hp0, r1, r0);
      *(vf4*)&cat1[sb][512 + sj] = r1;
      *(vf4*)&cat0[sb][256 + sj] = r0;

      if (tid < 512) {
        // spike bits -> floats (round-5 verified decode)
        int widx = tid >> 3, q = tid & 7;
        int h = widx & 1, s2 = widx >> 1;
        int bq = h * 4 + (q >> 1);
        int jh = q & 1;
        unsigned bits = (unsigned)(swords[widx] >> ((q >> 1) * 16 + jh * 8)) & 0xFFu;
        vf4 f0, f1;
        f0.x = (float)((bits >> 0) & 1); f0.y = (float)((bits >> 1) & 1);
        f0.z = (float)((bits >> 2) & 1); f0.w = (float)((bits >> 3) & 1);
        f1.x = (float)((bits >> 4) & 1); f1.y = (float)((bits >> 5) & 1);
        f1.z = (float)((bits >> 6) & 1); f1.w = (float)((bits >> 7) & 1);
        *(vf4*)&cat1[bq][s2 * 16 + jh * 8]     = f0;
        *(vf4*)&cat1[bq][s2 * 16 + jh * 8 + 4] = f1;

        // x(t+1) cached
        if (t < T - 1) {
          int bx = tid >> 6, kx = (tid & 63) * 4;
          *(vf4*)&cat0[bx][kx] =
              *(const vf4*)&x[(size_t)(g * 8 + bx) * (T * II) + (size_t)(t + 1) * II + kx];
        }
      }
    }
    __syncthreads();  // S4

    // ---------- dot1: [s0[t] ; h1[t-1]] @ Wc1 (K=1024) ----------
    {
      const vf4* wr = Wc1p + (size_t)j * 1024;
      vf4 acc = {0, 0, 0, 0};
#pragma unroll 4
      for (int q = 0; q < 32; ++q) {
        int k = q * 32 + kl * 4;
        vf4 w0 = wr[k], w1 = wr[k + 1], w2 = wr[k + 2], w3 = wr[k + 3];
        vf4 av = *(const vf4*)&cat1[b][k];
        acc += av.x * w0; acc += av.y * w1; acc += av.z * w2; acc += av.w * w3;
      }
      part[jo][b][kl] = acc;
    }
    __syncthreads();  // S5

    // ---------- finalize layer 1 ----------
    if (tid < 128) {
      vf4 p = part[fjo][fb][0];
#pragma unroll
      for (int kk = 1; kk < 8; ++kk) p += part[fjo][fb][kk];
      p += bh1p[fj];
      float cn  = sigf(p.y) * c1 + sigf(p.x) * tanh_fast(p.z);
      float hn  = sigf(p.w) * tanh_fast(cn);
      float h1n = hn * 0.2f + sp;             // output neuron: h*decay + input(spike)
      c1 = cn;
      bypass_st(&hx1[(t & 1) * 32768 + g * 4096 + fb * 512 + fj], h1n);
      out[(size_t)(g * 8 + fb) * (T * 512) + (size_t)t * 512 + fj] = h1n;
      if (t == T - 1) {
        out[HOFF + 32768 + (g * 8 + fb) * 512 + fj] = h1n;
        out[COFF + 32768 + (g * 8 + fb) * 512 + fj] = cn;
      }
    }
    __syncthreads();  // S6 — part[] reuse by next dot0
  }
}

// ---------------- launch ----------------
extern "C" void kernel_launch(void* const* d_in, const int* in_sizes, int n_in,
                              void* d_out, int out_size, void* d_ws, size_t ws_size,
                              hipStream_t stream) {
  const float* x   = (const float*)d_in[0];
  const float* Wx0 = (const float*)d_in[1];
  const float* Wh0 = (const float*)d_in[2];
  const float* bh0 = (const float*)d_in[3];
  const float* Wx1 = (const float*)d_in[4];
  const float* Wh1 = (const float*)d_in[5];
  const float* bh1 = (const float*)d_in[6];
  float* out = (float*)d_out;
  float* ws  = (float*)d_ws;

  float* Wc0p  = ws + WS_WC0;
  float* Wc1p  = ws + WS_WC1;
  float* bh0pf = ws + WS_BH0;
  float* bh1pf = ws + WS_BH1;
  float* hx0   = ws + WS_HX0;
  float* hx1   = ws + WS_HX1;
  unsigned long long* sx = (unsigned long long*)(ws + WS_SX);
  unsigned* flags = (unsigned*)(ws + WS_FLG);

  // zero: h exchanges (both slots), spike words, stamps, s1 output section
  hipMemsetAsync(hx0, 0, 2 * 64 * 512 * sizeof(float), stream);
  hipMemsetAsync(hx1, 0, 2 * 64 * 512 * sizeof(float), stream);
  hipMemsetAsync(sx, 0, 2048 * sizeof(unsigned long long), stream);
  hipMemsetAsync(flags, 0, 512 * sizeof(unsigned), stream);
  hipMemsetAsync(out + SOFF + BB * HH, 0, BB * HH * sizeof(float), stream);

  pack_wc<<<dim3(512), dim3(256), 0, stream>>>(Wx0, Wh0, 256, 768, Wc0p);
  pack_wc<<<dim3(512), dim3(256), 0, stream>>>(Wx1, Wh1, 512, 1024, Wc1p);
  pack_bias<<<dim3(16), dim3(256), 0, stream>>>(bh0, bh1, bh0pf, bh1pf);

  aslstm_main<<<dim3(256), dim3(1024), 0, stream>>>(
      (const vf4*)Wc0p, (const vf4*)Wc1p, (const vf4*)bh0pf, (const vf4*)bh1pf,
      x, hx0, hx1, sx, flags, out);
}

// Round 7
// 8865.984 us; speedup vs baseline: 3.0076x; 3.0076x over previous
//
#include <hip/hip_runtime.h>
#include <math.h>

typedef float vf4 __attribute__((ext_vector_type(4)));

// Problem dims (fixed by reference)
constexpr int T  = 512;
constexpr int BB = 64;    // batch
constexpr int II = 256;   // input
constexpr int HH = 512;   // hidden

// d_out layout (floats): out[B,T,H] | s[2,B,H] | h[2,B,H] | c[2,B,H]
constexpr int SOFF = BB * T * HH;          // 16777216
constexpr int HOFF = SOFF + 2 * BB * HH;
constexpr int COFF = HOFF + 2 * BB * HH;

// Workspace layout (float offsets). ~15.3 MB.
constexpr int WS_WC0 = 0;          // [512 j][768 k] vf4  (Wx0;Wh0 stacked)
constexpr int WS_WC1 = 1572864;    // [512 j][1024 k] vf4 (Wx1;Wh1 stacked)
constexpr int WS_BH0 = 3670016;    // [512] vf4
constexpr int WS_BH1 = 3672064;
constexpr int WS_HX0 = 3674112;    // h0 exchange: [2 slot][8 g][8 b][512 j] f
constexpr int WS_HX1 = 3739648;    // h1 exchange: same
constexpr int WS_SX  = 3805184;    // spike bytes: [4 slot][8 g][512 j] u8 = 16 KB
constexpr int WS_FLG = 3809280;    // stamps: [8 g][64] u32

// ---------------- MALL-coherent primitives: plain sc0 sc1 ops, no atomics ----
__device__ __forceinline__ void bypass_st(float* p, float v) {
  asm volatile("global_store_dword %0, %1, off sc0 sc1" :: "v"(p), "v"(v) : "memory");
}
__device__ __forceinline__ void bypass_st_u32(unsigned* p, unsigned v) {
  asm volatile("global_store_dword %0, %1, off sc0 sc1" :: "v"(p), "v"(v) : "memory");
}
__device__ __forceinline__ void bypass_st_u8(unsigned char* p, unsigned v) {
  asm volatile("global_store_byte %0, %1, off sc0 sc1" :: "v"(p), "v"(v) : "memory");
}
__device__ __forceinline__ unsigned bypass_ldu(const unsigned* p) {
  unsigned r;
  asm volatile("global_load_dword %0, %1, off sc0 sc1\n\ts_waitcnt vmcnt(0)"
               : "=v"(r) : "v"(p) : "memory");
  return r;
}
__device__ __forceinline__ unsigned long long bypass_ld64(const unsigned long long* p) {
  unsigned long long r;
  asm volatile("global_load_dwordx2 %0, %1, off sc0 sc1\n\ts_waitcnt vmcnt(0)"
               : "=v"(r) : "v"(p) : "memory");
  return r;
}
// two 16B loads, ONE wait (batched latency)
__device__ __forceinline__ void bypass_ld2x4(const vf4* p0, const vf4* p1, vf4& r0, vf4& r1) {
  asm volatile(
      "global_load_dwordx4 %0, %2, off sc0 sc1\n\t"
      "global_load_dwordx4 %1, %3, off sc0 sc1\n\t"
      "s_waitcnt vmcnt(0)"
      : "=&v"(r0), "=&v"(r1) : "v"(p0), "v"(p1) : "memory");
}

__device__ __forceinline__ float sigf(float x) { return 1.0f / (1.0f + __expf(-x)); }
__device__ __forceinline__ float tanh_fast(float x) {
  return 1.0f - 2.0f / (1.0f + __expf(2.0f * x));
}

__device__ __forceinline__ float sxor(float v, int m) { return __shfl_xor(v, m, 64); }
__device__ __forceinline__ vf4 sxor4(vf4 v, int m) {
  vf4 r; r.x = sxor(v.x, m); r.y = sxor(v.y, m); r.z = sxor(v.z, m); r.w = sxor(v.w, m);
  return r;
}

// 3-bit bit-reversal (self-inverse): lane<->batch map for the split butterfly
__device__ __forceinline__ int rev3(int v) {
  return ((v & 1) << 2) | (v & 2) | ((v >> 2) & 1);
}

// Batch-splitting butterfly: in: acc[8] = partials for batches 0..7 over this
// lane's k-chunk. out: complete wave-sum vf4 for batch rev3(kl&7) (8 replicas).
__device__ __forceinline__ vf4 reduce8(const vf4* acc, int kl) {
  const int sel = kl & 1;
  vf4 n0[4];
#pragma unroll
  for (int i = 0; i < 4; ++i) {
    vf4 snd = sel ? acc[i] : acc[i + 4];
    vf4 kp  = sel ? acc[i + 4] : acc[i];
    n0[i] = kp + sxor4(snd, 1);
  }
  const int sel2 = (kl >> 1) & 1;
  vf4 n1[2];
#pragma unroll
  for (int i = 0; i < 2; ++i) {
    vf4 snd = sel2 ? n0[i] : n0[i + 2];
    vf4 kp  = sel2 ? n0[i + 2] : n0[i];
    n1[i] = kp + sxor4(snd, 2);
  }
  const int sel3 = (kl >> 2) & 1;
  vf4 snd = sel3 ? n1[0] : n1[1];
  vf4 kp  = sel3 ? n1[1] : n1[0];
  vf4 r = kp + sxor4(snd, 4);
  r += sxor4(r, 8);
  r += sxor4(r, 16);
  r += sxor4(r, 32);
  return r;
}

// ---------------- setup kernels ----------------
// Wp[j][k] f4 = gates (i,f,g,o) of column j, act-row k; rows k<Ka from A, else B.
__global__ void pack_wc(const float* __restrict__ A, const float* __restrict__ B,
                        int Ka, int K, float* __restrict__ Wp) {
  const int j = blockIdx.x;
  for (int k = threadIdx.x; k < K; k += 256) {
    const float* src = (k < Ka) ? (A + (size_t)k * 2048) : (B + (size_t)(k - Ka) * 2048);
    vf4 v = {src[j], src[512 + j], src[1024 + j], src[1536 + j]};
    ((vf4*)Wp)[(size_t)j * K + k] = v;
  }
}

__global__ void pack_bias(const float* __restrict__ bh0, const float* __restrict__ bh1,
                          float* __restrict__ bh0p, float* __restrict__ bh1p) {
  const int i = blockIdx.x * blockDim.x + threadIdx.x;  // 4096
  if (i < 2048) {
    bh0p[i] = bh0[(i & 3) * 512 + (i >> 2)];
  } else {
    int q = i - 2048;
    bh1p[q] = bh1[(q & 3) * 512 + (q >> 2)];
  }
}

// ---------------- main persistent kernel ----------------
// Round 7: R=1 weight loads + in-register finalize.
// 256 blocks x 1024 threads (16 waves, 1 block/CU).
//   xcd = wg&7; a = wg>>3; g = a&7 (8 batches); s = (a>>3)*8 + xcd in [0,32)
//   (16 j-cols) -> per-XCD unique weights 1.83 MB, L2-resident (r5-verified).
// Dot: wave jo = tid>>6 owns column j = s*16+jo; lane kl = tid&63 owns
//   k = ig*256 + kl*4 + {0..3}. Weight vf4 loaded ONCE per CU (R=1, coalesced
//   4KB/wave/group); all 8 batches accumulated in registers (acc = 8 vf4).
// Reduction: batch-splitting shuffle butterfly -> lane kl holds the complete
//   gate vf4 for batch rev3(kl&7) (8 replicas, bitwise consistent).
//   Gates/spike/c-state all in registers: no part[] LDS, 3 syncs/step.
// Spike exchange: per-wave byte (ballot low 8 bits, bit l = batch rev3(l)).
// Sync: stamp-store + poll barrier, all sc0 sc1 (r5/r6-verified protocol).
__global__ __launch_bounds__(1024, 1) void aslstm_main(
    const vf4* __restrict__ Wc0p, const vf4* __restrict__ Wc1p,
    const vf4* __restrict__ bh0p, const vf4* __restrict__ bh1p,
    const float* __restrict__ x,
    float* __restrict__ hx0, float* __restrict__ hx1,
    unsigned char* __restrict__ sxb,
    unsigned* __restrict__ flags,
    float* __restrict__ out) {
  const int wg  = blockIdx.x;
  const int xcd = wg & 7;
  const int a   = wg >> 3;
  const int g   = a & 7;
  const int s   = (a >> 3) * 8 + xcd;
  const int tid = threadIdx.x;
  const int jo  = tid >> 6;          // wave -> j column
  const int kl  = tid & 63;          // lane -> k chunk
  const int j   = s * 16 + jo;
  const int b_loc  = rev3(kl & 7);   // batch this lane finalizes (8 replicas)
  const int b_glob = g * 8 + b_loc;
  const bool rep0  = (kl < 8);       // replica 0 does the stores

  __shared__ float cat0[8][776];     // [b][ x(256) | h0(512) | pad ]
  __shared__ float cat1[8][1032];    // [b][ s0(512) | h1(512) | pad ]
  __shared__ unsigned long long swords[64];   // 512 spike bytes for this group

  float c0 = 0.0f, c1 = 0.0f, sp = 0.0f;

  // staging indices: one vf4 of h per thread per buffer
  const int sb2 = tid >> 7;          // b_loc row 0..7
  const int sj2 = (tid & 127) * 4;   // j 0..508 step 4

  // ---- initial cat0: x[t=0] + h0[-1]=0 (hx0 slot 1 is memset) ----
  {
    if (tid < 512) {
      int bx = tid >> 6, kx = (tid & 63) * 4;
      *(vf4*)&cat0[bx][kx] = *(const vf4*)&x[(size_t)(g * 8 + bx) * (T * II) + kx];
    }
    const vf4* hp = (const vf4*)(hx0 + 32768 + g * 4096 + sb2 * 512 + sj2);
    vf4 r0, r1;  bypass_ld2x4(hp, hp, r0, r1);
    *(vf4*)&cat0[sb2][256 + sj2] = r0;
  }
  __syncthreads();

  for (int t = 0; t < T; ++t) {
    // ---------- dot0: [x_t ; h0[t-1]] @ Wc0 (K=768), R=1 weight loads ----------
    vf4 acc[8];
#pragma unroll
    for (int b = 0; b < 8; ++b) acc[b] = vf4{0, 0, 0, 0};
    {
      const vf4* wr = Wc0p + (size_t)j * 768;
#pragma unroll
      for (int ig = 0; ig < 3; ++ig) {
        const int k0 = ig * 256 + kl * 4;
        vf4 w0 = wr[k0], w1 = wr[k0 + 1], w2 = wr[k0 + 2], w3 = wr[k0 + 3];
#pragma unroll
        for (int b = 0; b < 8; ++b) {
          vf4 av = *(const vf4*)&cat0[b][k0];
          acc[b] += av.x * w0; acc[b] += av.y * w1;
          acc[b] += av.z * w2; acc[b] += av.w * w3;
        }
      }
    }

    // ---------- in-wave reduce + finalize layer 0 (registers only) ----------
    {
      vf4 p = reduce8(acc, kl) + bh0p[j];
      float cn  = sigf(p.y) * c0 + sigf(p.x) * tanh_fast(p.z);
      float mem = sigf(p.w) * tanh_fast(cn);   // s*0.2*(1-s) == 0 for s in {0,1}
      float sn  = (mem > 0.5f) ? 1.0f : 0.0f;
      c0 = cn; sp = sn;
      unsigned long long ball = __ballot(sn != 0.0f);
      if (rep0) {
        bypass_st(&hx0[(t & 1) * 32768 + g * 4096 + b_loc * 512 + j], mem);
        if (kl == 0)
          bypass_st_u8(&sxb[(size_t)(t & 3) * 4096 + g * 512 + j],
                       (unsigned)(ball & 0xFFull));
        if (t == T - 1) {
          out[SOFF + b_glob * 512 + j] = sn;
          out[HOFF + b_glob * 512 + j] = mem;
          out[COFF + b_glob * 512 + j] = cn;
        }
      }
    }
    __syncthreads();  // S1 — each wave drains vmcnt before s_barrier => publishes visible

    // ---------- group barrier: stamp store + poll (no atomics) ----------
    if (tid == 0) bypass_st_u32(&flags[g * 64 + s], (unsigned)(t + 1));
    if (tid < 64) {
      const unsigned tgt = (unsigned)(t + 1);
      for (;;) {
        unsigned v = bypass_ldu(&flags[g * 64 + (tid & 31)]);
        if (__all((int)(v >= tgt))) break;
        __builtin_amdgcn_s_sleep(1);
      }
      swords[tid] = bypass_ld64(
          (const unsigned long long*)(sxb + (size_t)(t & 3) * 4096 + g * 512) + tid);
    }
    __syncthreads();  // S3

    // ---------- staging: cat1(s0 bits, h1[t-1]) + cat0(x[t+1], h0[t]) ----------
    {
      const vf4* hp1 = (const vf4*)(hx1 + ((t + 1) & 1) * 32768 + g * 4096 + sb2 * 512 + sj2);
      const vf4* hp0 = (const vf4*)(hx0 + (t & 1) * 32768 + g * 4096 + sb2 * 512 + sj2);
      vf4 r1, r0;  bypass_ld2x4(hp1, hp0, r1, r0);
      *(vf4*)&cat1[sb2][512 + sj2] = r1;
      *(vf4*)&cat0[sb2][256 + sj2] = r0;

      if (tid < 512) {
        // spike byte -> 8 batch floats for column jd (bit rev3(b) = spike(b))
        const int jd = tid;
        unsigned byte = ((const unsigned char*)swords)[jd];
#pragma unroll
        for (int b = 0; b < 8; ++b)
          cat1[b][jd] = (float)((byte >> rev3(b)) & 1u);

        if (t < T - 1) {
          int bx = tid >> 6, kx = (tid & 63) * 4;
          *(vf4*)&cat0[bx][kx] =
              *(const vf4*)&x[(size_t)(g * 8 + bx) * (T * II) + (size_t)(t + 1) * II + kx];
        }
      }
    }
    __syncthreads();  // S4

    // ---------- dot1: [s0[t] ; h1[t-1]] @ Wc1 (K=1024), R=1 ----------
#pragma unroll
    for (int b = 0; b < 8; ++b) acc[b] = vf4{0, 0, 0, 0};
    {
      const vf4* wr = Wc1p + (size_t)j * 1024;
#pragma unroll
      for (int ig = 0; ig < 4; ++ig) {
        const int k0 = ig * 256 + kl * 4;
        vf4 w0 = wr[k0], w1 = wr[k0 + 1], w2 = wr[k0 + 2], w3 = wr[k0 + 3];
#pragma unroll
        for (int b = 0; b < 8; ++b) {
          vf4 av = *(const vf4*)&cat1[b][k0];
          acc[b] += av.x * w0; acc[b] += av.y * w1;
          acc[b] += av.z * w2; acc[b] += av.w * w3;
        }
      }
    }

    // ---------- in-wave reduce + finalize layer 1 (registers only) ----------
    {
      vf4 p = reduce8(acc, kl) + bh1p[j];
      float cn  = sigf(p.y) * c1 + sigf(p.x) * tanh_fast(p.z);
      float hn  = sigf(p.w) * tanh_fast(cn);
      float h1n = hn * 0.2f + sp;              // output neuron: h*decay + input(spike)
      c1 = cn;
      if (rep0) {
        bypass_st(&hx1[(t & 1) * 32768 + g * 4096 + b_loc * 512 + j], h1n);
        out[(size_t)b_glob * (T * HH) + (size_t)t * HH + j] = h1n;
        if (t == T - 1) {
          out[HOFF + 32768 + b_glob * 512 + j] = h1n;
          out[COFF + 32768 + b_glob * 512 + j] = cn;
        }
      }
    }
    // no sync needed: cat0(t+1) staged before S4; next write to LDS is after S3(t+1)
  }
}

// ---------------- launch ----------------
extern "C" void kernel_launch(void* const* d_in, const int* in_sizes, int n_in,
                              void* d_out, int out_size, void* d_ws, size_t ws_size,
                              hipStream_t stream) {
  const float* x   = (const float*)d_in[0];
  const float* Wx0 = (const float*)d_in[1];
  const float* Wh0 = (const float*)d_in[2];
  const float* bh0 = (const float*)d_in[3];
  const float* Wx1 = (const float*)d_in[4];
  const float* Wh1 = (const float*)d_in[5];
  const float* bh1 = (const float*)d_in[6];
  float* out = (float*)d_out;
  float* ws  = (float*)d_ws;

  float* Wc0p  = ws + WS_WC0;
  float* Wc1p  = ws + WS_WC1;
  float* bh0pf = ws + WS_BH0;
  float* bh1pf = ws + WS_BH1;
  float* hx0   = ws + WS_HX0;
  float* hx1   = ws + WS_HX1;
  unsigned char* sxb = (unsigned char*)(ws + WS_SX);
  unsigned* flags = (unsigned*)(ws + WS_FLG);

  // zero: h exchanges (both slots), spike bytes, stamps, s1 output section
  hipMemsetAsync(hx0, 0, 2 * 64 * 512 * sizeof(float), stream);
  hipMemsetAsync(hx1, 0, 2 * 64 * 512 * sizeof(float), stream);
  hipMemsetAsync(sxb, 0, 16384, stream);
  hipMemsetAsync(flags, 0, 512 * sizeof(unsigned), stream);
  hipMemsetAsync(out + SOFF + BB * HH, 0, BB * HH * sizeof(float), stream);

  pack_wc<<<dim3(512), dim3(256), 0, stream>>>(Wx0, Wh0, 256, 768, Wc0p);
  pack_wc<<<dim3(512), dim3(256), 0, stream>>>(Wx1, Wh1, 512, 1024, Wc1p);
  pack_bias<<<dim3(16), dim3(256), 0, stream>>>(bh0, bh1, bh0pf, bh1pf);

  aslstm_main<<<dim3(256), dim3(1024), 0, stream>>>(
      (const vf4*)Wc0p, (const vf4*)Wc1p, (const vf4*)bh0pf, (const vf4*)bh1pf,
      x, hx0, hx1, sxb, flags, out);
}